// Round 1
// baseline (441.918 us; speedup 1.0000x reference)
//
#include <hip/hip_runtime.h>
#include <hip/hip_bf16.h>
#include <math.h>

typedef unsigned short u16;
typedef unsigned int u32;
typedef __attribute__((ext_vector_type(8))) short short8;
typedef __attribute__((ext_vector_type(8))) unsigned short ushort8;
typedef __attribute__((ext_vector_type(4))) float floatx4;

// Problem constants: B=2, T=2048, C=1024, H=16, D=64; BT = B*T = 4096.
#define BTROWS 4096
#define CDIM   1024
#define TSEQ   2048
#define NHEAD  16
#define HDIM   64

static __device__ __forceinline__ u16 f2bf(float f) {
    u32 u = __float_as_uint(f);
    u += 0x7fffu + ((u >> 16) & 1u);   // RNE
    return (u16)(u >> 16);
}
static __device__ __forceinline__ float bf2f(u16 h) {
    return __uint_as_float(((u32)h) << 16);
}

// ---------------------------------------------------------------------------
// prep_x: xa = tanh(x) as bf16, x_sq[row] = sum(tanh(x)^2) in f32
// grid 4096 x 256
__global__ __launch_bounds__(256) void prep_x(const float* __restrict__ x,
                                              u16* __restrict__ xa,
                                              float* __restrict__ xsq) {
    int row = blockIdx.x, tid = threadIdx.x;
    const float4* xr = reinterpret_cast<const float4*>(x + (size_t)row * CDIM);
    float4 v = xr[tid];
    float a0 = tanhf(v.x), a1 = tanhf(v.y), a2 = tanhf(v.z), a3 = tanhf(v.w);
    ushort4 bv = make_ushort4(f2bf(a0), f2bf(a1), f2bf(a2), f2bf(a3));
    *reinterpret_cast<ushort4*>(xa + (size_t)row * CDIM + tid * 4) = bv;
    float s = a0*a0 + a1*a1 + a2*a2 + a3*a3;
    #pragma unroll
    for (int m = 1; m < 64; m <<= 1) s += __shfl_xor(s, m, 64);
    __shared__ float red[4];
    if ((tid & 63) == 0) red[tid >> 6] = s;
    __syncthreads();
    if (tid == 0) xsq[row] = red[0] + red[1] + red[2] + red[3];
}

// ---------------------------------------------------------------------------
// prep_w: mats 0..2 = tanh(W{q,k,v}) -> bf16 + w_sq; mat 3 = Wo -> bf16
// grid 4096 x 256  (blockIdx>>10 = mat, &1023 = row)
__global__ __launch_bounds__(256) void prep_w(const float* __restrict__ Wq, const float* __restrict__ Wk,
                                              const float* __restrict__ Wv, const float* __restrict__ Wo,
                                              u16* __restrict__ waq, u16* __restrict__ wak,
                                              u16* __restrict__ wav, u16* __restrict__ wob,
                                              float* __restrict__ sqq, float* __restrict__ sqk,
                                              float* __restrict__ sqv) {
    int mat = blockIdx.x >> 10, row = blockIdx.x & 1023, tid = threadIdx.x;
    const float* W = (mat == 0) ? Wq : (mat == 1) ? Wk : (mat == 2) ? Wv : Wo;
    u16* outp      = (mat == 0) ? waq : (mat == 1) ? wak : (mat == 2) ? wav : wob;
    float4 v = reinterpret_cast<const float4*>(W + (size_t)row * CDIM)[tid];
    if (mat < 3) {
        float a0 = tanhf(v.x), a1 = tanhf(v.y), a2 = tanhf(v.z), a3 = tanhf(v.w);
        *reinterpret_cast<ushort4*>(outp + (size_t)row * CDIM + tid * 4) =
            make_ushort4(f2bf(a0), f2bf(a1), f2bf(a2), f2bf(a3));
        float s = a0*a0 + a1*a1 + a2*a2 + a3*a3;
        #pragma unroll
        for (int m = 1; m < 64; m <<= 1) s += __shfl_xor(s, m, 64);
        __shared__ float red[4];
        if ((tid & 63) == 0) red[tid >> 6] = s;
        __syncthreads();
        if (tid == 0) {
            float* sq = (mat == 0) ? sqq : (mat == 1) ? sqk : sqv;
            sq[row] = red[0] + red[1] + red[2] + red[3];
        }
    } else {
        *reinterpret_cast<ushort4*>(outp + (size_t)row * CDIM + tid * 4) =
            make_ushort4(f2bf(v.x), f2bf(v.y), f2bf(v.z), f2bf(v.w));
    }
}

// ---------------------------------------------------------------------------
// gemm_bt<EPI>: C[m][n] = sum_k A[m][k]*Bm[n][k]  (both row-major, K contiguous)
// EPI 0: q/k projection -> tanh((1 - clip(xsq+wsq-2dot)/1024 - .5)*gain) bf16 row-major
// EPI 1: v projection   -> same w/o tanh, stored TRANSPOSED per head: vT[b][h][d][t]
// EPI 2: plain f32 store (final Wo GEMM)
// tile 128x128, BK=32, 256 thr (4 waves, 2x2 of 64x64)
template <int EPI>
__global__ __launch_bounds__(256) void gemm_bt(const u16* __restrict__ A, const u16* __restrict__ Bm,
                                               float* __restrict__ outF, u16* __restrict__ outH,
                                               const float* __restrict__ xsq, const float* __restrict__ wsq,
                                               const float* __restrict__ gain) {
    __shared__ __align__(16) u16 As[128 * 40];
    __shared__ __align__(16) u16 Bs[128 * 40];
    int tid = threadIdx.x;
    int m0 = blockIdx.y * 128, n0 = blockIdx.x * 128;
    int w = tid >> 6, l = tid & 63, wm = w >> 1, wn = w & 1, g = l >> 4, c = l & 15;

    floatx4 acc[4][4] = {};

    int srow = tid >> 1, scol = (tid & 1) * 16;
    const ushort8* gA = reinterpret_cast<const ushort8*>(A + (size_t)(m0 + srow) * CDIM + scol);
    const ushort8* gB = reinterpret_cast<const ushort8*>(Bm + (size_t)(n0 + srow) * CDIM + scol);
    u16* wA = &As[srow * 40 + scol];
    u16* wB = &Bs[srow * 40 + scol];

    for (int kt = 0; kt < 32; ++kt) {
        ushort8 a0 = gA[0], a1 = gA[1], b0 = gB[0], b1 = gB[1];
        gA += 4; gB += 4;
        __syncthreads();
        *reinterpret_cast<ushort8*>(wA)     = a0;
        *reinterpret_cast<ushort8*>(wA + 8) = a1;
        *reinterpret_cast<ushort8*>(wB)     = b0;
        *reinterpret_cast<ushort8*>(wB + 8) = b1;
        __syncthreads();
        short8 af[4], bf[4];
        #pragma unroll
        for (int mi = 0; mi < 4; mi++)
            af[mi] = *reinterpret_cast<const short8*>(&As[(wm * 64 + mi * 16 + c) * 40 + g * 8]);
        #pragma unroll
        for (int ni = 0; ni < 4; ni++)
            bf[ni] = *reinterpret_cast<const short8*>(&Bs[(wn * 64 + ni * 16 + c) * 40 + g * 8]);
        #pragma unroll
        for (int mi = 0; mi < 4; mi++)
            #pragma unroll
            for (int ni = 0; ni < 4; ni++)
                acc[mi][ni] = __builtin_amdgcn_mfma_f32_16x16x32_bf16(af[mi], bf[ni], acc[mi][ni], 0, 0, 0);
    }

    #pragma unroll
    for (int mi = 0; mi < 4; mi++) {
        int rowb = m0 + wm * 64 + mi * 16 + g * 4;
        #pragma unroll
        for (int ni = 0; ni < 4; ni++) {
            int col = n0 + wn * 64 + ni * 16 + c;
            if (EPI == 2) {
                #pragma unroll
                for (int r = 0; r < 4; r++)
                    outF[(size_t)(rowb + r) * CDIM + col] = acc[mi][ni][r];
            } else {
                float wsqc = wsq[col], gn = gain[col];
                float vals[4];
                #pragma unroll
                for (int r = 0; r < 4; r++) {
                    float dot = acc[mi][ni][r];
                    float l2 = fmaxf(xsq[rowb + r] + wsqc - 2.f * dot, 0.f);
                    float o = 1.f - l2 * (1.f / 1024.f);
                    vals[r] = (o - 0.5f) * gn;
                }
                if (EPI == 0) {
                    #pragma unroll
                    for (int r = 0; r < 4; r++)
                        outH[(size_t)(rowb + r) * CDIM + col] = f2bf(tanhf(vals[r]));
                } else {  // EPI == 1: vT[b][h][d][t]
                    int bb = rowb >> 11, t0 = rowb & 2047;
                    int hh = col >> 6, dd = col & 63;
                    ushort4 pv = make_ushort4(f2bf(vals[0]), f2bf(vals[1]), f2bf(vals[2]), f2bf(vals[3]));
                    *reinterpret_cast<ushort4*>(&outH[(((size_t)(bb * NHEAD + hh) * HDIM + dd) << 11) + t0]) = pv;
                }
            }
        }
    }
}

// ---------------------------------------------------------------------------
// sq_rows: qsq[(b*T+t)*16+h] = sum_d q[t,h*64+d]^2 ; same for k.  grid 4096 x 256
__global__ __launch_bounds__(256) void sq_rows(const u16* __restrict__ q, const u16* __restrict__ k,
                                               float* __restrict__ qsq, float* __restrict__ ksq) {
    int row = blockIdx.x, tid = threadIdx.x;
    int which = tid >> 7, rem = tid & 127, h = rem >> 3, ln = rem & 7;
    const u16* src = which ? k : q;
    ushort8 vv = *reinterpret_cast<const ushort8*>(&src[(size_t)row * CDIM + h * HDIM + ln * 8]);
    float s = 0.f;
    #pragma unroll
    for (int j = 0; j < 8; j++) { float f = bf2f(vv[j]); s += f * f; }
    s += __shfl_xor(s, 1, 64);
    s += __shfl_xor(s, 2, 64);
    s += __shfl_xor(s, 4, 64);
    if (ln == 0) (which ? ksq : qsq)[row * NHEAD + h] = s;
}

// ---------------------------------------------------------------------------
// attn: flash attention over distance logits. grid (32 ttiles, 16 h, 2 b) x 256.
// Each wave owns 16 t-rows; loops 32 s-tiles of 64.
__global__ __launch_bounds__(256) void attn(const u16* __restrict__ q, const u16* __restrict__ k,
                                            const u16* __restrict__ vT, const float* __restrict__ qsq,
                                            const float* __restrict__ ksq, u16* __restrict__ ao) {
    int tt = blockIdx.x, h = blockIdx.y, b = blockIdx.z;
    int tid = threadIdx.x, w = tid >> 6, l = tid & 63, g = l >> 4, c = l & 15;
    int t0 = tt * 64 + w * 16;

    __shared__ __align__(16) float Sbuf[4][16][68];
    __shared__ __align__(16) u16 Pbuf[4][16][72];
    __shared__ float mL[4][16], lL[4][16], fL[4][16], qsL[4][16];

    size_t qbase = ((size_t)(b * TSEQ + t0 + c)) * CDIM + h * HDIM;
    short8 aq0 = *reinterpret_cast<const short8*>(&q[qbase + g * 8]);
    short8 aq1 = *reinterpret_cast<const short8*>(&q[qbase + 32 + g * 8]);

    if (l < 16) {
        mL[w][l] = -INFINITY;
        lL[w][l] = 0.f;
        qsL[w][l] = qsq[(size_t)(b * TSEQ + t0 + l) * NHEAD + h];
    }
    floatx4 oacc[4] = {};
    __syncthreads();

    int r4 = l >> 2, q4 = l & 3;

    for (int st = 0; st < 32; ++st) {
        int s0 = st * 64;
        // ---- S = Q.K^T tile (16 x 64) per wave
        floatx4 sacc[4];
        #pragma unroll
        for (int ni = 0; ni < 4; ni++) {
            size_t kbase = ((size_t)(b * TSEQ + s0 + ni * 16 + c)) * CDIM + h * HDIM;
            short8 bk0 = *reinterpret_cast<const short8*>(&k[kbase + g * 8]);
            short8 bk1 = *reinterpret_cast<const short8*>(&k[kbase + 32 + g * 8]);
            floatx4 z = {0.f, 0.f, 0.f, 0.f};
            z = __builtin_amdgcn_mfma_f32_16x16x32_bf16(aq0, bk0, z, 0, 0, 0);
            z = __builtin_amdgcn_mfma_f32_16x16x32_bf16(aq1, bk1, z, 0, 0, 0);
            sacc[ni] = z;
        }
        #pragma unroll
        for (int ni = 0; ni < 4; ni++)
            #pragma unroll
            for (int r = 0; r < 4; r++)
                Sbuf[w][g * 4 + r][ni * 16 + c] = sacc[ni][r];
        __syncthreads();

        // ---- online softmax: 4 lanes per row (row = l>>2), 16 s-vals per lane
        float qs = qsL[w][r4];
        const float* ksrow = ksq + ((size_t)(b * TSEQ + s0) * NHEAD + h);
        float lg[16];
        float tmax = -INFINITY;
        #pragma unroll
        for (int j = 0; j < 16; j++) {
            int s = q4 + 4 * j;
            float dot = Sbuf[w][r4][s];
            float dist = fmaxf(qs + ksrow[s * NHEAD] - 2.f * dot, 0.f);
            lg[j] = -dist * (1.f / 80.f);
            tmax = fmaxf(tmax, lg[j]);
        }
        tmax = fmaxf(tmax, __shfl_xor(tmax, 1, 64));
        tmax = fmaxf(tmax, __shfl_xor(tmax, 2, 64));
        float m_old = mL[w][r4];
        float m_new = fmaxf(m_old, tmax);
        float fac = __expf(m_old - m_new);
        float psum = 0.f;
        #pragma unroll
        for (int j = 0; j < 16; j++) {
            float p = __expf(lg[j] - m_new);
            psum += p;
            Pbuf[w][r4][q4 + 4 * j] = f2bf(p);
        }
        psum += __shfl_xor(psum, 1, 64);
        psum += __shfl_xor(psum, 2, 64);
        if (q4 == 0) {
            mL[w][r4] = m_new;
            lL[w][r4] = lL[w][r4] * fac + psum;
            fL[w][r4] = fac;
        }
        __syncthreads();

        // ---- rescale O, then O += P.V
        float fr[4];
        #pragma unroll
        for (int r = 0; r < 4; r++) fr[r] = fL[w][g * 4 + r];
        #pragma unroll
        for (int ni = 0; ni < 4; ni++)
            #pragma unroll
            for (int r = 0; r < 4; r++) oacc[ni][r] *= fr[r];

        short8 ap0 = *reinterpret_cast<const short8*>(&Pbuf[w][c][g * 8]);
        short8 ap1 = *reinterpret_cast<const short8*>(&Pbuf[w][c][32 + g * 8]);
        #pragma unroll
        for (int ni = 0; ni < 4; ni++) {
            size_t vb = ((size_t)((b * NHEAD + h) * HDIM + ni * 16 + c)) * TSEQ + s0;
            short8 bv0 = *reinterpret_cast<const short8*>(&vT[vb + g * 8]);
            short8 bv1 = *reinterpret_cast<const short8*>(&vT[vb + 32 + g * 8]);
            oacc[ni] = __builtin_amdgcn_mfma_f32_16x16x32_bf16(ap0, bv0, oacc[ni], 0, 0, 0);
            oacc[ni] = __builtin_amdgcn_mfma_f32_16x16x32_bf16(ap1, bv1, oacc[ni], 0, 0, 0);
        }
        __syncthreads();
    }

    float linv[4];
    #pragma unroll
    for (int r = 0; r < 4; r++) linv[r] = 1.f / lL[w][g * 4 + r];
    #pragma unroll
    for (int ni = 0; ni < 4; ni++)
        #pragma unroll
        for (int r = 0; r < 4; r++)
            ao[(size_t)(b * TSEQ + t0 + g * 4 + r) * CDIM + h * HDIM + ni * 16 + c] =
                f2bf(oacc[ni][r] * linv[r]);
}

// ---------------------------------------------------------------------------
extern "C" void kernel_launch(void* const* d_in, const int* in_sizes, int n_in,
                              void* d_out, int out_size, void* d_ws, size_t ws_size,
                              hipStream_t stream) {
    const float* x  = (const float*)d_in[0];
    const float* Wq = (const float*)d_in[1];
    const float* gq = (const float*)d_in[2];
    const float* Wk = (const float*)d_in[3];
    const float* gk = (const float*)d_in[4];
    const float* Wv = (const float*)d_in[5];
    const float* gv = (const float*)d_in[6];
    const float* Wo = (const float*)d_in[7];
    float* out = (float*)d_out;

    char* p = (char*)d_ws;
    u16* xa  = (u16*)p;  p += (size_t)8 << 20;
    u16* qb  = (u16*)p;  p += (size_t)8 << 20;
    u16* kb  = (u16*)p;  p += (size_t)8 << 20;
    u16* vT  = (u16*)p;  p += (size_t)8 << 20;
    u16* ao  = (u16*)p;  p += (size_t)8 << 20;
    u16* waq = (u16*)p;  p += (size_t)2 << 20;
    u16* wak = (u16*)p;  p += (size_t)2 << 20;
    u16* wav = (u16*)p;  p += (size_t)2 << 20;
    u16* wob = (u16*)p;  p += (size_t)2 << 20;
    float* xsq  = (float*)p; p += 4096 * 4;
    float* sqq  = (float*)p; p += 1024 * 4;
    float* sqk  = (float*)p; p += 1024 * 4;
    float* sqv  = (float*)p; p += 1024 * 4;
    float* qsq  = (float*)p; p += 4096 * 16 * 4;
    float* ksq  = (float*)p; p += 4096 * 16 * 4;
    (void)ws_size; (void)in_sizes; (void)n_in; (void)out_size;

    prep_x<<<4096, 256, 0, stream>>>(x, xa, xsq);
    prep_w<<<4096, 256, 0, stream>>>(Wq, Wk, Wv, Wo, waq, wak, wav, wob, sqq, sqk, sqv);

    dim3 gg(8, 32);
    gemm_bt<0><<<gg, 256, 0, stream>>>(xa, waq, nullptr, qb, xsq, sqq, gq);
    gemm_bt<0><<<gg, 256, 0, stream>>>(xa, wak, nullptr, kb, xsq, sqk, gk);
    gemm_bt<1><<<gg, 256, 0, stream>>>(xa, wav, nullptr, vT, xsq, sqv, gv);

    sq_rows<<<4096, 256, 0, stream>>>(qb, kb, qsq, ksq);

    dim3 ga(32, 16, 2);
    attn<<<ga, 256, 0, stream>>>(qb, kb, vT, qsq, ksq, ao);

    gemm_bt<2><<<gg, 256, 0, stream>>>(ao, wob, out, nullptr, nullptr, nullptr, nullptr);
}

// Round 2
// 178.365 us; speedup vs baseline: 2.4776x; 2.4776x over previous
//
#include <hip/hip_runtime.h>
#include <hip/hip_bf16.h>
#include <math.h>

typedef unsigned short u16;
typedef unsigned int u32;
typedef __attribute__((ext_vector_type(8))) short short8;
typedef __attribute__((ext_vector_type(8))) unsigned short ushort8;
typedef __attribute__((ext_vector_type(4))) float floatx4;

#define CDIM   1024
#define TSEQ   2048
#define NHEAD  16
#define HDIM   64

static __device__ __forceinline__ u16 f2bf(float f) {
    u32 u = __float_as_uint(f);
    u += 0x7fffu + ((u >> 16) & 1u);   // RNE
    return (u16)(u >> 16);
}
static __device__ __forceinline__ float bf2f(u16 h) {
    return __uint_as_float(((u32)h) << 16);
}

// async global->LDS, 16 bytes per lane. LDS dest: wave-uniform base + lane*16.
static __device__ __forceinline__ void gll16(const void* g, void* l) {
    __builtin_amdgcn_global_load_lds(
        (const __attribute__((address_space(1))) unsigned int*)g,
        (__attribute__((address_space(3))) unsigned int*)l, 16, 0, 0);
}

// ---------------------------------------------------------------------------
// prep_x: xa = tanh(x) bf16, xsq[row] = sum(tanh^2). grid 4096 x 256
__global__ __launch_bounds__(256) void prep_x(const float* __restrict__ x,
                                              u16* __restrict__ xa,
                                              float* __restrict__ xsq) {
    int row = blockIdx.x, tid = threadIdx.x;
    float4 v = reinterpret_cast<const float4*>(x + (size_t)row * CDIM)[tid];
    float a0 = tanhf(v.x), a1 = tanhf(v.y), a2 = tanhf(v.z), a3 = tanhf(v.w);
    *reinterpret_cast<ushort4*>(xa + (size_t)row * CDIM + tid * 4) =
        make_ushort4(f2bf(a0), f2bf(a1), f2bf(a2), f2bf(a3));
    float s = a0*a0 + a1*a1 + a2*a2 + a3*a3;
    #pragma unroll
    for (int m = 1; m < 64; m <<= 1) s += __shfl_xor(s, m, 64);
    __shared__ float red[4];
    if ((tid & 63) == 0) red[tid >> 6] = s;
    __syncthreads();
    if (tid == 0) xsq[row] = red[0] + red[1] + red[2] + red[3];
}

// ---------------------------------------------------------------------------
// prep_w: mats 0..2 = tanh(W) bf16 + wsq; mat 3 = Wo bf16. grid 4096 x 256
__global__ __launch_bounds__(256) void prep_w(const float* __restrict__ Wq, const float* __restrict__ Wk,
                                              const float* __restrict__ Wv, const float* __restrict__ Wo,
                                              u16* __restrict__ waq, u16* __restrict__ wak,
                                              u16* __restrict__ wav, u16* __restrict__ wob,
                                              float* __restrict__ sqq, float* __restrict__ sqk,
                                              float* __restrict__ sqv) {
    int mat = blockIdx.x >> 10, row = blockIdx.x & 1023, tid = threadIdx.x;
    const float* W = (mat == 0) ? Wq : (mat == 1) ? Wk : (mat == 2) ? Wv : Wo;
    u16* outp      = (mat == 0) ? waq : (mat == 1) ? wak : (mat == 2) ? wav : wob;
    float4 v = reinterpret_cast<const float4*>(W + (size_t)row * CDIM)[tid];
    if (mat < 3) {
        float a0 = tanhf(v.x), a1 = tanhf(v.y), a2 = tanhf(v.z), a3 = tanhf(v.w);
        *reinterpret_cast<ushort4*>(outp + (size_t)row * CDIM + tid * 4) =
            make_ushort4(f2bf(a0), f2bf(a1), f2bf(a2), f2bf(a3));
        float s = a0*a0 + a1*a1 + a2*a2 + a3*a3;
        #pragma unroll
        for (int m = 1; m < 64; m <<= 1) s += __shfl_xor(s, m, 64);
        __shared__ float red[4];
        if ((tid & 63) == 0) red[tid >> 6] = s;
        __syncthreads();
        if (tid == 0) {
            float* sq = (mat == 0) ? sqq : (mat == 1) ? sqk : sqv;
            sq[row] = red[0] + red[1] + red[2] + red[3];
        }
    } else {
        *reinterpret_cast<ushort4*>(outp + (size_t)row * CDIM + tid * 4) =
            make_ushort4(f2bf(v.x), f2bf(v.y), f2bf(v.z), f2bf(v.w));
    }
}

// ---------------------------------------------------------------------------
// Fused QKV GEMM: C = A * Bm^T with distance epilogue; z = 0(q)/1(k)/2(v).
// m97 structure: 128x128 tile, BK=32, global_load_lds(16B), 2-bit XOR swizzle.
__global__ __launch_bounds__(256) void gemm_qkv(const u16* __restrict__ xa,
                                                const u16* __restrict__ waq, const u16* __restrict__ wak, const u16* __restrict__ wav,
                                                u16* __restrict__ qb, u16* __restrict__ kb, u16* __restrict__ vT,
                                                const float* __restrict__ xsq,
                                                const float* __restrict__ sqq, const float* __restrict__ sqk, const float* __restrict__ sqv,
                                                const float* __restrict__ gq, const float* __restrict__ gk, const float* __restrict__ gv) {
    __shared__ __align__(16) u16 As[128 * 32];
    __shared__ __align__(16) u16 Bs[128 * 32];
    int z = blockIdx.z;
    const u16* Bm = (z == 0) ? waq : (z == 1) ? wak : wav;
    const float* wsq = (z == 0) ? sqq : (z == 1) ? sqk : sqv;
    const float* gain = (z == 0) ? gq : (z == 1) ? gk : gv;

    int tid = threadIdx.x;
    int m0 = blockIdx.y * 128, n0 = blockIdx.x * 128;
    int w = tid >> 6, l = tid & 63, wm = w >> 1, wn = w & 1, g = l >> 4, c = l & 15;

    floatx4 acc[4][4] = {};
    int rch = l >> 2;                      // row within chunk (0..15)
    int sl2 = (l & 3) ^ (rch & 3);         // pre-swizzled 16B slot (0..3)

    for (int kt = 0; kt < 32; ++kt) {
        __syncthreads();                   // prev-iter readers done
        #pragma unroll
        for (int i = 0; i < 2; i++) {
            int ch = w * 2 + i;
            int row = ch * 16 + rch;
            gll16(xa + (size_t)(m0 + row) * CDIM + kt * 32 + sl2 * 8, &As[ch * 512 + l * 8]);
            gll16(Bm + (size_t)(n0 + row) * CDIM + kt * 32 + sl2 * 8, &Bs[ch * 512 + l * 8]);
        }
        __syncthreads();                   // vmcnt drained -> tiles visible
        short8 af[4], bf[4];
        #pragma unroll
        for (int mi = 0; mi < 4; mi++)
            af[mi] = *reinterpret_cast<const short8*>(&As[(wm * 64 + mi * 16 + c) * 32 + ((g ^ (c & 3)) << 3)]);
        #pragma unroll
        for (int ni = 0; ni < 4; ni++)
            bf[ni] = *reinterpret_cast<const short8*>(&Bs[(wn * 64 + ni * 16 + c) * 32 + ((g ^ (c & 3)) << 3)]);
        #pragma unroll
        for (int mi = 0; mi < 4; mi++)
            #pragma unroll
            for (int ni = 0; ni < 4; ni++)
                acc[mi][ni] = __builtin_amdgcn_mfma_f32_16x16x32_bf16(af[mi], bf[ni], acc[mi][ni], 0, 0, 0);
    }

    #pragma unroll
    for (int mi = 0; mi < 4; mi++) {
        int rowb = m0 + wm * 64 + mi * 16 + g * 4;
        #pragma unroll
        for (int ni = 0; ni < 4; ni++) {
            int col = n0 + wn * 64 + ni * 16 + c;
            float wsqc = wsq[col], gn = gain[col];
            float vals[4];
            #pragma unroll
            for (int r = 0; r < 4; r++) {
                float l2 = fmaxf(xsq[rowb + r] + wsqc - 2.f * acc[mi][ni][r], 0.f);
                vals[r] = (1.f - l2 * (1.f / 1024.f) - 0.5f) * gn;
            }
            if (z < 2) {
                u16* outH = (z == 0) ? qb : kb;
                #pragma unroll
                for (int r = 0; r < 4; r++)
                    outH[(size_t)(rowb + r) * CDIM + col] = f2bf(tanhf(vals[r]));
            } else {  // v: store transposed per head vT[b][h][d][t]
                int bb = rowb >> 11, t0 = rowb & 2047;
                int hh = col >> 6, dd = col & 63;
                ushort4 pv = make_ushort4(f2bf(vals[0]), f2bf(vals[1]), f2bf(vals[2]), f2bf(vals[3]));
                *reinterpret_cast<ushort4*>(&vT[(((size_t)(bb * NHEAD + hh) * HDIM + dd) << 11) + t0]) = pv;
            }
        }
    }
}

// ---------------------------------------------------------------------------
// Final GEMM: out = ao * Wo^T, f32 store. Same m97 structure.
__global__ __launch_bounds__(256) void gemm_out(const u16* __restrict__ A, const u16* __restrict__ Bm,
                                                float* __restrict__ outF) {
    __shared__ __align__(16) u16 As[128 * 32];
    __shared__ __align__(16) u16 Bs[128 * 32];
    int tid = threadIdx.x;
    int m0 = blockIdx.y * 128, n0 = blockIdx.x * 128;
    int w = tid >> 6, l = tid & 63, wm = w >> 1, wn = w & 1, g = l >> 4, c = l & 15;

    floatx4 acc[4][4] = {};
    int rch = l >> 2;
    int sl2 = (l & 3) ^ (rch & 3);

    for (int kt = 0; kt < 32; ++kt) {
        __syncthreads();
        #pragma unroll
        for (int i = 0; i < 2; i++) {
            int ch = w * 2 + i;
            int row = ch * 16 + rch;
            gll16(A + (size_t)(m0 + row) * CDIM + kt * 32 + sl2 * 8, &As[ch * 512 + l * 8]);
            gll16(Bm + (size_t)(n0 + row) * CDIM + kt * 32 + sl2 * 8, &Bs[ch * 512 + l * 8]);
        }
        __syncthreads();
        short8 af[4], bf[4];
        #pragma unroll
        for (int mi = 0; mi < 4; mi++)
            af[mi] = *reinterpret_cast<const short8*>(&As[(wm * 64 + mi * 16 + c) * 32 + ((g ^ (c & 3)) << 3)]);
        #pragma unroll
        for (int ni = 0; ni < 4; ni++)
            bf[ni] = *reinterpret_cast<const short8*>(&Bs[(wn * 64 + ni * 16 + c) * 32 + ((g ^ (c & 3)) << 3)]);
        #pragma unroll
        for (int mi = 0; mi < 4; mi++)
            #pragma unroll
            for (int ni = 0; ni < 4; ni++)
                acc[mi][ni] = __builtin_amdgcn_mfma_f32_16x16x32_bf16(af[mi], bf[ni], acc[mi][ni], 0, 0, 0);
    }

    #pragma unroll
    for (int mi = 0; mi < 4; mi++) {
        int rowb = m0 + wm * 64 + mi * 16 + g * 4;
        #pragma unroll
        for (int ni = 0; ni < 4; ni++) {
            int col = n0 + wn * 64 + ni * 16 + c;
            #pragma unroll
            for (int r = 0; r < 4; r++)
                outF[(size_t)(rowb + r) * CDIM + col] = acc[mi][ni][r];
        }
    }
}

// ---------------------------------------------------------------------------
// sq_rows: qsqT[(b*16+h)*2048+t] = sum_d q[t,h*64+d]^2 ; same for k. grid 4096 x 256
__global__ __launch_bounds__(256) void sq_rows(const u16* __restrict__ q, const u16* __restrict__ k,
                                               float* __restrict__ qsqT, float* __restrict__ ksqT) {
    int row = blockIdx.x, tid = threadIdx.x;
    int which = tid >> 7, rem = tid & 127, h = rem >> 3, ln = rem & 7;
    const u16* src = which ? k : q;
    ushort8 vv = *reinterpret_cast<const ushort8*>(&src[(size_t)row * CDIM + h * HDIM + ln * 8]);
    float s = 0.f;
    #pragma unroll
    for (int j = 0; j < 8; j++) { float f = bf2f(vv[j]); s += f * f; }
    s += __shfl_xor(s, 1, 64);
    s += __shfl_xor(s, 2, 64);
    s += __shfl_xor(s, 4, 64);
    if (ln == 0) {
        int b = row >> 11, t = row & 2047;
        (which ? ksqT : qsqT)[(size_t)(b * NHEAD + h) * TSEQ + t] = s;
    }
}

// ---------------------------------------------------------------------------
// attn v2: swapped QK^T, in-register online softmax, LDS-staged K/V (dbuf,
// global_load_lds + XOR swizzle), per-wave P bounce. grid (16, 16, 2) x 256.
// Block = 4 waves x 32 q-rows = 128 rows; loop 32 s-tiles of 64.
__global__ __launch_bounds__(256) void attn2(const u16* __restrict__ q, const u16* __restrict__ k,
                                             const u16* __restrict__ vT, const float* __restrict__ qsqT,
                                             const float* __restrict__ ksqT, u16* __restrict__ ao) {
    int tt = blockIdx.x, h = blockIdx.y, b = blockIdx.z;
    int tid = threadIdx.x, w = tid >> 6, l = tid & 63, g = l >> 4, c = l & 15;
    int tw = tt * 128 + w * 32;

    __shared__ __align__(16) u16 Ks[2][64 * 64];   // [s][d], d-slots XOR-swizzled
    __shared__ __align__(16) u16 Vs[2][64 * 64];   // [d][s], s-slots XOR-swizzled
    __shared__ __align__(16) u16 Ps[4][32][72];    // per-wave P tile
    __shared__ float fLs[4][2][16], lLs[4][2][16];

    // Q as B-fragments (col = t), loaded once.
    short8 qf[2][2];
    float qs[2];
    #pragma unroll
    for (int tf = 0; tf < 2; tf++) {
        size_t qrow = (size_t)(b * TSEQ + tw + tf * 16 + c) * CDIM + h * HDIM;
        qf[tf][0] = *reinterpret_cast<const short8*>(&q[qrow + g * 8]);
        qf[tf][1] = *reinterpret_cast<const short8*>(&q[qrow + 32 + g * 8]);
        qs[tf] = qsqT[(size_t)(b * NHEAD + h) * TSEQ + tw + tf * 16 + c];
    }
    const float* ksb = ksqT + (size_t)(b * NHEAD + h) * TSEQ;
    const u16* kbase = k + (size_t)(b * TSEQ) * CDIM + h * HDIM;
    const u16* vbase = vT + (size_t)(b * NHEAD + h) * HDIM * TSEQ;

    int r8 = l >> 3, sl = (l & 7) ^ r8;   // chunk-row, pre-swizzled 16B slot

    floatx4 oacc[2][4] = {};
    float mrun[2] = {-INFINITY, -INFINITY}, lrun[2] = {0.f, 0.f};

    // prologue: stage tile 0 into buffer 0
    {
        int s0 = 0;
        #pragma unroll
        for (int i = 0; i < 2; i++) {
            int ch = w * 2 + i;
            gll16(kbase + (size_t)(s0 + ch * 8 + r8) * CDIM + sl * 8, &Ks[0][ch * 512 + l * 8]);
            gll16(vbase + (size_t)(ch * 8 + r8) * TSEQ + s0 + sl * 8, &Vs[0][ch * 512 + l * 8]);
        }
    }
    __syncthreads();

    for (int st = 0; st < 32; ++st) {
        int cur = st & 1;
        if (st < 31) {
            int s1 = (st + 1) * 64;
            #pragma unroll
            for (int i = 0; i < 2; i++) {
                int ch = w * 2 + i;
                gll16(kbase + (size_t)(s1 + ch * 8 + r8) * CDIM + sl * 8, &Ks[cur ^ 1][ch * 512 + l * 8]);
                gll16(vbase + (size_t)(ch * 8 + r8) * TSEQ + s1 + sl * 8, &Vs[cur ^ 1][ch * 512 + l * 8]);
            }
        }

        // ---- S^T = K . Q^T : rows = s, cols = t (per-lane: 16 s-values for t=c)
        short8 kf[4][2];
        #pragma unroll
        for (int si = 0; si < 4; si++)
            #pragma unroll
            for (int kc = 0; kc < 2; kc++)
                kf[si][kc] = *reinterpret_cast<const short8*>(
                    &Ks[cur][(si * 16 + c) * 64 + (((kc * 4 + g) ^ (c & 7)) << 3)]);
        floatx4 sacc[2][4] = {};
        #pragma unroll
        for (int tf = 0; tf < 2; tf++)
            #pragma unroll
            for (int si = 0; si < 4; si++) {
                sacc[tf][si] = __builtin_amdgcn_mfma_f32_16x16x32_bf16(kf[si][0], qf[tf][0], sacc[tf][si], 0, 0, 0);
                sacc[tf][si] = __builtin_amdgcn_mfma_f32_16x16x32_bf16(kf[si][1], qf[tf][1], sacc[tf][si], 0, 0, 0);
            }

        float4 kq[4];
        #pragma unroll
        for (int si = 0; si < 4; si++)
            kq[si] = *reinterpret_cast<const float4*>(&ksb[st * 64 + si * 16 + g * 4]);

        // ---- online softmax, fully in-register (reduce over lanes c, c+16, c+32, c+48)
        #pragma unroll
        for (int tf = 0; tf < 2; tf++) {
            float lg[4][4];
            float tmax = -INFINITY;
            #pragma unroll
            for (int si = 0; si < 4; si++) {
                float kqa[4] = {kq[si].x, kq[si].y, kq[si].z, kq[si].w};
                #pragma unroll
                for (int r = 0; r < 4; r++) {
                    float dist = fmaxf(qs[tf] + kqa[r] - 2.f * sacc[tf][si][r], 0.f);
                    lg[si][r] = dist * (-1.f / 80.f);
                    tmax = fmaxf(tmax, lg[si][r]);
                }
            }
            tmax = fmaxf(tmax, __shfl_xor(tmax, 16, 64));
            tmax = fmaxf(tmax, __shfl_xor(tmax, 32, 64));
            float mnew = fmaxf(mrun[tf], tmax);
            float fac = __expf(mrun[tf] - mnew);
            mrun[tf] = mnew;
            float psum = 0.f;
            #pragma unroll
            for (int si = 0; si < 4; si++) {
                ushort4 pw;
                float p0 = __expf(lg[si][0] - mnew), p1 = __expf(lg[si][1] - mnew);
                float p2 = __expf(lg[si][2] - mnew), p3 = __expf(lg[si][3] - mnew);
                psum += p0 + p1 + p2 + p3;
                pw = make_ushort4(f2bf(p0), f2bf(p1), f2bf(p2), f2bf(p3));
                *reinterpret_cast<ushort4*>(&Ps[w][tf * 16 + c][si * 16 + g * 4]) = pw;
            }
            psum += __shfl_xor(psum, 16, 64);
            psum += __shfl_xor(psum, 32, 64);
            lrun[tf] = lrun[tf] * fac + psum;
            if (g == 0) fLs[w][tf][c] = fac;
        }

        // ---- rescale O (factor indexed by output-row layout), then O += P.V
        #pragma unroll
        for (int tf = 0; tf < 2; tf++) {
            float fr[4];
            #pragma unroll
            for (int r = 0; r < 4; r++) fr[r] = fLs[w][tf][g * 4 + r];
            #pragma unroll
            for (int di = 0; di < 4; di++)
                #pragma unroll
                for (int r = 0; r < 4; r++) oacc[tf][di][r] *= fr[r];
        }

        short8 pa[2][2];
        #pragma unroll
        for (int tf = 0; tf < 2; tf++)
            #pragma unroll
            for (int sc = 0; sc < 2; sc++)
                pa[tf][sc] = *reinterpret_cast<const short8*>(&Ps[w][tf * 16 + c][sc * 32 + g * 8]);
        #pragma unroll
        for (int di = 0; di < 4; di++)
            #pragma unroll
            for (int sc = 0; sc < 2; sc++) {
                short8 vf = *reinterpret_cast<const short8*>(
                    &Vs[cur][(di * 16 + c) * 64 + (((sc * 4 + g) ^ (c & 7)) << 3)]);
                #pragma unroll
                for (int tf = 0; tf < 2; tf++)
                    oacc[tf][di] = __builtin_amdgcn_mfma_f32_16x16x32_bf16(pa[tf][sc], vf, oacc[tf][di], 0, 0, 0);
            }

        __syncthreads();   // all waves done with cur; next tile staged & drained
    }

    if (g == 0) { lLs[w][0][c] = lrun[0]; lLs[w][1][c] = lrun[1]; }
    #pragma unroll
    for (int tf = 0; tf < 2; tf++) {
        float linv[4];
        #pragma unroll
        for (int r = 0; r < 4; r++) linv[r] = 1.f / lLs[w][tf][g * 4 + r];
        #pragma unroll
        for (int di = 0; di < 4; di++)
            #pragma unroll
            for (int r = 0; r < 4; r++)
                ao[(size_t)(b * TSEQ + tw + tf * 16 + g * 4 + r) * CDIM + h * HDIM + di * 16 + c] =
                    f2bf(oacc[tf][di][r] * linv[r]);
    }
}

// ---------------------------------------------------------------------------
extern "C" void kernel_launch(void* const* d_in, const int* in_sizes, int n_in,
                              void* d_out, int out_size, void* d_ws, size_t ws_size,
                              hipStream_t stream) {
    const float* x  = (const float*)d_in[0];
    const float* Wq = (const float*)d_in[1];
    const float* gq = (const float*)d_in[2];
    const float* Wk = (const float*)d_in[3];
    const float* gk = (const float*)d_in[4];
    const float* Wv = (const float*)d_in[5];
    const float* gv = (const float*)d_in[6];
    const float* Wo = (const float*)d_in[7];
    float* out = (float*)d_out;

    char* p = (char*)d_ws;
    u16* xa  = (u16*)p;  p += (size_t)8 << 20;
    u16* qb  = (u16*)p;  p += (size_t)8 << 20;
    u16* kb  = (u16*)p;  p += (size_t)8 << 20;
    u16* vT  = (u16*)p;  p += (size_t)8 << 20;
    u16* ao  = (u16*)p;  p += (size_t)8 << 20;
    u16* waq = (u16*)p;  p += (size_t)2 << 20;
    u16* wak = (u16*)p;  p += (size_t)2 << 20;
    u16* wav = (u16*)p;  p += (size_t)2 << 20;
    u16* wob = (u16*)p;  p += (size_t)2 << 20;
    float* xsq  = (float*)p; p += 4096 * 4;
    float* sqq  = (float*)p; p += 1024 * 4;
    float* sqk  = (float*)p; p += 1024 * 4;
    float* sqv  = (float*)p; p += 1024 * 4;
    float* qsqT = (float*)p; p += 4096 * 16 * 4;
    float* ksqT = (float*)p; p += 4096 * 16 * 4;
    (void)ws_size; (void)in_sizes; (void)n_in; (void)out_size;

    prep_x<<<4096, 256, 0, stream>>>(x, xa, xsq);
    prep_w<<<4096, 256, 0, stream>>>(Wq, Wk, Wv, Wo, waq, wak, wav, wob, sqq, sqk, sqv);

    dim3 gqkv(8, 32, 3);
    gemm_qkv<<<gqkv, 256, 0, stream>>>(xa, waq, wak, wav, qb, kb, vT, xsq,
                                       sqq, sqk, sqv, gq, gk, gv);

    sq_rows<<<4096, 256, 0, stream>>>(qb, kb, qsqT, ksqT);

    dim3 ga(16, NHEAD, 2);
    attn2<<<ga, 256, 0, stream>>>(qb, kb, vT, qsqT, ksqT, ao);

    dim3 gg(8, 32);
    gemm_out<<<gg, 256, 0, stream>>>(ao, wob, out);
}

// Round 3
// 171.267 us; speedup vs baseline: 2.5803x; 1.0414x over previous
//
#include <hip/hip_runtime.h>
#include <hip/hip_bf16.h>
#include <math.h>

typedef unsigned short u16;
typedef unsigned int u32;
typedef __attribute__((ext_vector_type(8))) short short8;
typedef __attribute__((ext_vector_type(8))) unsigned short ushort8;
typedef __attribute__((ext_vector_type(4))) float floatx4;
typedef __attribute__((ext_vector_type(2))) unsigned int uint2v;

#define CDIM   1024
#define TSEQ   2048
#define NHEAD  16
#define HDIM   64

static __device__ __forceinline__ u16 f2bf(float f) {
    u32 u = __float_as_uint(f);
    u += 0x7fffu + ((u >> 16) & 1u);   // RNE
    return (u16)(u >> 16);
}

// packed f32x2 -> bf16x2 (RNE), single VOP3
static __device__ __forceinline__ u32 cvtpk(float a, float b) {
    u32 r;
    asm("v_cvt_pk_bf16_f32 %0, %1, %2" : "=v"(r) : "v"(a), "v"(b));
    return r;
}

// fast tanh: 1 - 2/(exp2(2x*log2e)+1). ~1e-7 rel err, correct saturation.
static __device__ __forceinline__ float ftanh(float x) {
    float e = exp2f(x * 2.88539008f);
    float r = __builtin_amdgcn_rcpf(e + 1.0f);
    return fmaf(-2.0f, r, 1.0f);
}

// async global->LDS, 16 bytes per lane (lane 0's ptr = wave base).
static __device__ __forceinline__ void gll16(const void* g, void* l) {
    __builtin_amdgcn_global_load_lds(
        (const __attribute__((address_space(1))) unsigned int*)g,
        (__attribute__((address_space(3))) unsigned int*)l, 16, 0, 0);
}

// ---------------------------------------------------------------------------
// prep: bid<4096 -> xa=tanh(x)+xsq ; else W mats (tanh+wsq for q/k/v, copy Wo)
__global__ __launch_bounds__(256) void prep(const float* __restrict__ x,
                                            const float* __restrict__ Wq, const float* __restrict__ Wk,
                                            const float* __restrict__ Wv, const float* __restrict__ Wo,
                                            u16* __restrict__ xa,
                                            u16* __restrict__ waq, u16* __restrict__ wak,
                                            u16* __restrict__ wav, u16* __restrict__ wob,
                                            float* __restrict__ xsq,
                                            float* __restrict__ sqq, float* __restrict__ sqk,
                                            float* __restrict__ sqv) {
    __shared__ float red[4];
    int bid = blockIdx.x, tid = threadIdx.x;
    const float* src; u16* dst; float* sq; int row; bool do_tanh = true;
    if (bid < 4096) {
        row = bid; src = x; dst = xa; sq = xsq;
    } else {
        int mat = (bid - 4096) >> 10; row = (bid - 4096) & 1023;
        src = (mat == 0) ? Wq : (mat == 1) ? Wk : (mat == 2) ? Wv : Wo;
        dst = (mat == 0) ? waq : (mat == 1) ? wak : (mat == 2) ? wav : wob;
        sq  = (mat == 0) ? sqq : (mat == 1) ? sqk : (mat == 2) ? sqv : nullptr;
        do_tanh = (mat < 3);
    }
    float4 v = reinterpret_cast<const float4*>(src + (size_t)row * CDIM)[tid];
    if (do_tanh) {
        float a0 = ftanh(v.x), a1 = ftanh(v.y), a2 = ftanh(v.z), a3 = ftanh(v.w);
        *reinterpret_cast<ushort4*>(dst + (size_t)row * CDIM + tid * 4) =
            make_ushort4(f2bf(a0), f2bf(a1), f2bf(a2), f2bf(a3));
        float s = a0*a0 + a1*a1 + a2*a2 + a3*a3;
        #pragma unroll
        for (int m = 1; m < 64; m <<= 1) s += __shfl_xor(s, m, 64);
        if ((tid & 63) == 0) red[tid >> 6] = s;
        __syncthreads();
        if (tid == 0 && sq) sq[row] = red[0] + red[1] + red[2] + red[3];
    } else {
        *reinterpret_cast<ushort4*>(dst + (size_t)row * CDIM + tid * 4) =
            make_ushort4(f2bf(v.x), f2bf(v.y), f2bf(v.z), f2bf(v.w));
    }
}

// ---------------------------------------------------------------------------
// Fused QKV GEMM: C = A * Bm^T, distance epilogue; z = 0(q)/1(k)/2(v).
// 128x128 tile, BK=64, global_load_lds(16B), 4-bit XOR swizzle (row&7 ^ row>>3&1).
// q/k epilogue also computes per-head row sq -> qsqT/ksqT (replaces sq_rows).
__global__ __launch_bounds__(256) void gemm_qkv(const u16* __restrict__ xa,
                                                const u16* __restrict__ waq, const u16* __restrict__ wak, const u16* __restrict__ wav,
                                                u16* __restrict__ qb, u16* __restrict__ kb, u16* __restrict__ vT,
                                                const float* __restrict__ xsq,
                                                const float* __restrict__ sqq, const float* __restrict__ sqk, const float* __restrict__ sqv,
                                                const float* __restrict__ gq, const float* __restrict__ gk, const float* __restrict__ gv,
                                                float* __restrict__ qsqT, float* __restrict__ ksqT) {
    __shared__ __align__(16) u16 As[128 * 64];
    __shared__ __align__(16) u16 Bs[128 * 64];
    int z = blockIdx.z;
    const u16* Bm   = (z == 0) ? waq : (z == 1) ? wak : wav;
    const float* wsq  = (z == 0) ? sqq : (z == 1) ? sqk : sqv;
    const float* gain = (z == 0) ? gq : (z == 1) ? gk : gv;

    int tid = threadIdx.x;
    int m0 = blockIdx.y * 128, n0 = blockIdx.x * 128;
    int w = tid >> 6, l = tid & 63, wm = w >> 1, wn = w & 1, g = l >> 4, c = l & 15;
    int r8 = l >> 3, sl7 = l & 7;
    int cmask = (c & 7) ^ (c >> 3);

    floatx4 acc[4][4] = {};

    for (int kt = 0; kt < 16; ++kt) {
        __syncthreads();                   // prev-iter readers done
        #pragma unroll
        for (int i = 0; i < 4; i++) {
            int ch = w * 4 + i;
            int row = ch * 8 + r8;
            int sl = sl7 ^ r8 ^ (ch & 1);
            gll16(xa + (size_t)(m0 + row) * CDIM + kt * 64 + sl * 8, &As[ch * 512 + l * 8]);
            gll16(Bm + (size_t)(n0 + row) * CDIM + kt * 64 + sl * 8, &Bs[ch * 512 + l * 8]);
        }
        __syncthreads();                   // staged tile visible
        short8 af[2][4], bf[2][4];
        #pragma unroll
        for (int kk = 0; kk < 2; kk++) {
            #pragma unroll
            for (int mi = 0; mi < 4; mi++)
                af[kk][mi] = *reinterpret_cast<const short8*>(
                    &As[(wm * 64 + mi * 16 + c) * 64 + (((kk * 4 + g) ^ cmask) << 3)]);
            #pragma unroll
            for (int ni = 0; ni < 4; ni++)
                bf[kk][ni] = *reinterpret_cast<const short8*>(
                    &Bs[(wn * 64 + ni * 16 + c) * 64 + (((kk * 4 + g) ^ cmask) << 3)]);
        }
        #pragma unroll
        for (int kk = 0; kk < 2; kk++)
            #pragma unroll
            for (int mi = 0; mi < 4; mi++)
                #pragma unroll
                for (int ni = 0; ni < 4; ni++)
                    acc[mi][ni] = __builtin_amdgcn_mfma_f32_16x16x32_bf16(af[kk][mi], bf[kk][ni], acc[mi][ni], 0, 0, 0);
    }

    if (z < 2) {
        u16* outH = (z == 0) ? qb : kb;
        float* sqo = (z == 0) ? qsqT : ksqT;
        int hh = blockIdx.x * 2 + wn;      // this wave's head (64 cols)
        float part[4][4] = {};
        #pragma unroll
        for (int mi = 0; mi < 4; mi++) {
            int rowb = m0 + wm * 64 + mi * 16 + g * 4;
            #pragma unroll
            for (int ni = 0; ni < 4; ni++) {
                int col = n0 + wn * 64 + ni * 16 + c;
                float wsqc = wsq[col], gn = gain[col];
                #pragma unroll
                for (int r = 0; r < 4; r++) {
                    float l2 = fmaxf(xsq[rowb + r] + wsqc - 2.f * acc[mi][ni][r], 0.f);
                    float th = ftanh((0.5f - l2 * (1.f / 1024.f)) * gn);
                    outH[(size_t)(rowb + r) * CDIM + col] = f2bf(th);
                    part[mi][r] += th * th;
                }
            }
        }
        #pragma unroll
        for (int mi = 0; mi < 4; mi++)
            #pragma unroll
            for (int r = 0; r < 4; r++) {
                float s = part[mi][r];
                s += __shfl_xor(s, 1, 64); s += __shfl_xor(s, 2, 64);
                s += __shfl_xor(s, 4, 64); s += __shfl_xor(s, 8, 64);
                if (c == 0) {
                    int row = m0 + wm * 64 + mi * 16 + g * 4 + r;
                    int bb = row >> 11, t = row & 2047;
                    sqo[(size_t)(bb * NHEAD + hh) * TSEQ + t] = s;
                }
            }
    } else {  // v: (no tanh) store transposed per head vT[b][h][d][t]
        #pragma unroll
        for (int mi = 0; mi < 4; mi++) {
            int rowb = m0 + wm * 64 + mi * 16 + g * 4;
            #pragma unroll
            for (int ni = 0; ni < 4; ni++) {
                int col = n0 + wn * 64 + ni * 16 + c;
                float wsqc = wsq[col], gn = gain[col];
                float vals[4];
                #pragma unroll
                for (int r = 0; r < 4; r++) {
                    float l2 = fmaxf(xsq[rowb + r] + wsqc - 2.f * acc[mi][ni][r], 0.f);
                    vals[r] = (0.5f - l2 * (1.f / 1024.f)) * gn;
                }
                int bb = rowb >> 11, t0 = rowb & 2047;
                int hh = col >> 6, dd = col & 63;
                ushort4 pv = make_ushort4(f2bf(vals[0]), f2bf(vals[1]), f2bf(vals[2]), f2bf(vals[3]));
                *reinterpret_cast<ushort4*>(&vT[(((size_t)(bb * NHEAD + hh) * HDIM + dd) << 11) + t0]) = pv;
            }
        }
    }
}

// ---------------------------------------------------------------------------
// Final GEMM: out = ao * Wo^T, f32 store. Same BK=64 structure.
__global__ __launch_bounds__(256) void gemm_out(const u16* __restrict__ A, const u16* __restrict__ Bm,
                                                float* __restrict__ outF) {
    __shared__ __align__(16) u16 As[128 * 64];
    __shared__ __align__(16) u16 Bs[128 * 64];
    int tid = threadIdx.x;
    int m0 = blockIdx.y * 128, n0 = blockIdx.x * 128;
    int w = tid >> 6, l = tid & 63, wm = w >> 1, wn = w & 1, g = l >> 4, c = l & 15;
    int r8 = l >> 3, sl7 = l & 7;
    int cmask = (c & 7) ^ (c >> 3);

    floatx4 acc[4][4] = {};

    for (int kt = 0; kt < 16; ++kt) {
        __syncthreads();
        #pragma unroll
        for (int i = 0; i < 4; i++) {
            int ch = w * 4 + i;
            int row = ch * 8 + r8;
            int sl = sl7 ^ r8 ^ (ch & 1);
            gll16(A + (size_t)(m0 + row) * CDIM + kt * 64 + sl * 8, &As[ch * 512 + l * 8]);
            gll16(Bm + (size_t)(n0 + row) * CDIM + kt * 64 + sl * 8, &Bs[ch * 512 + l * 8]);
        }
        __syncthreads();
        short8 af[2][4], bf[2][4];
        #pragma unroll
        for (int kk = 0; kk < 2; kk++) {
            #pragma unroll
            for (int mi = 0; mi < 4; mi++)
                af[kk][mi] = *reinterpret_cast<const short8*>(
                    &As[(wm * 64 + mi * 16 + c) * 64 + (((kk * 4 + g) ^ cmask) << 3)]);
            #pragma unroll
            for (int ni = 0; ni < 4; ni++)
                bf[kk][ni] = *reinterpret_cast<const short8*>(
                    &Bs[(wn * 64 + ni * 16 + c) * 64 + (((kk * 4 + g) ^ cmask) << 3)]);
        }
        #pragma unroll
        for (int kk = 0; kk < 2; kk++)
            #pragma unroll
            for (int mi = 0; mi < 4; mi++)
                #pragma unroll
                for (int ni = 0; ni < 4; ni++)
                    acc[mi][ni] = __builtin_amdgcn_mfma_f32_16x16x32_bf16(af[kk][mi], bf[kk][ni], acc[mi][ni], 0, 0, 0);
    }

    #pragma unroll
    for (int mi = 0; mi < 4; mi++) {
        int rowb = m0 + wm * 64 + mi * 16 + g * 4;
        #pragma unroll
        for (int ni = 0; ni < 4; ni++) {
            int col = n0 + wn * 64 + ni * 16 + c;
            #pragma unroll
            for (int r = 0; r < 4; r++)
                outF[(size_t)(rowb + r) * CDIM + col] = acc[mi][ni][r];
        }
    }
}

// ---------------------------------------------------------------------------
// attn3: swapped QK^T, FIXED-m softmax (logits in [-3.2,0] => no max tracking,
// no rescale), exp2 folding, cvt_pk P-pack, dbuf LDS K/V with 4-bit XOR swizzle.
// grid (16, 16, 2) x 256; 4 waves x 32 q-rows; 32 s-tiles of 64.
__global__ __launch_bounds__(256) void attn3(const u16* __restrict__ q, const u16* __restrict__ k,
                                             const u16* __restrict__ vT, const float* __restrict__ qsqT,
                                             const float* __restrict__ ksqT, u16* __restrict__ ao) {
    int tt = blockIdx.x, h = blockIdx.y, b = blockIdx.z;
    int tid = threadIdx.x, w = tid >> 6, l = tid & 63, g = l >> 4, c = l & 15;
    int tw = tt * 128 + w * 32;

    __shared__ __align__(16) u16 Ks[2][64 * 64];   // [s][d-slots], XOR-swizzled
    __shared__ __align__(16) u16 Vs[2][64 * 64];   // [d][s-slots], XOR-swizzled
    __shared__ __align__(16) u16 Ps[4][32 * 64];   // per-wave P, XOR-swizzled
    __shared__ float lLs[4][2][16];

    const float C2 = -0.018033688f;    // -1/(80 ln2):  exp(-d/80) = exp2(d*C2)
    const float M2C2 = 0.036067376f;   // -2*C2

    short8 qf[2][2];
    float qsC[2];
    #pragma unroll
    for (int tf = 0; tf < 2; tf++) {
        size_t qrow = (size_t)(b * TSEQ + tw + tf * 16 + c) * CDIM + h * HDIM;
        qf[tf][0] = *reinterpret_cast<const short8*>(&q[qrow + g * 8]);
        qf[tf][1] = *reinterpret_cast<const short8*>(&q[qrow + 32 + g * 8]);
        qsC[tf] = qsqT[(size_t)(b * NHEAD + h) * TSEQ + tw + tf * 16 + c] * C2;
    }
    const float* ksb = ksqT + (size_t)(b * NHEAD + h) * TSEQ;
    const u16* kbase = k + (size_t)(b * TSEQ) * CDIM + h * HDIM;
    const u16* vbase = vT + (size_t)(b * NHEAD + h) * HDIM * TSEQ;

    int r8 = l >> 3, sl7 = l & 7;
    int cmask = (c & 7) ^ (c >> 3);

    floatx4 oacc[2][4] = {};
    float lrun[2] = {0.f, 0.f};

    // prologue: stage tile 0
    #pragma unroll
    for (int i = 0; i < 2; i++) {
        int ch = w * 2 + i;
        int sl = sl7 ^ r8 ^ (ch & 1);
        gll16(kbase + (size_t)(ch * 8 + r8) * CDIM + sl * 8, &Ks[0][ch * 512 + l * 8]);
        gll16(vbase + (size_t)(ch * 8 + r8) * TSEQ + sl * 8, &Vs[0][ch * 512 + l * 8]);
    }
    __syncthreads();

    for (int st = 0; st < 32; ++st) {
        int cur = st & 1;
        if (st < 31) {
            int s1 = (st + 1) * 64;
            #pragma unroll
            for (int i = 0; i < 2; i++) {
                int ch = w * 2 + i;
                int sl = sl7 ^ r8 ^ (ch & 1);
                gll16(kbase + (size_t)(s1 + ch * 8 + r8) * CDIM + sl * 8, &Ks[cur ^ 1][ch * 512 + l * 8]);
                gll16(vbase + (size_t)(ch * 8 + r8) * TSEQ + s1 + sl * 8, &Vs[cur ^ 1][ch * 512 + l * 8]);
            }
        }

        // ---- S^T = K.Q^T : lane holds s = si*16 + g*4 + r, t = c
        short8 kf[4][2];
        #pragma unroll
        for (int si = 0; si < 4; si++)
            #pragma unroll
            for (int kc = 0; kc < 2; kc++)
                kf[si][kc] = *reinterpret_cast<const short8*>(
                    &Ks[cur][(si * 16 + c) * 64 + (((kc * 4 + g) ^ cmask) << 3)]);
        floatx4 sacc[2][4] = {};
        #pragma unroll
        for (int tf = 0; tf < 2; tf++)
            #pragma unroll
            for (int si = 0; si < 4; si++) {
                sacc[tf][si] = __builtin_amdgcn_mfma_f32_16x16x32_bf16(kf[si][0], qf[tf][0], sacc[tf][si], 0, 0, 0);
                sacc[tf][si] = __builtin_amdgcn_mfma_f32_16x16x32_bf16(kf[si][1], qf[tf][1], sacc[tf][si], 0, 0, 0);
            }

        float4 kq[4];
        #pragma unroll
        for (int si = 0; si < 4; si++)
            kq[si] = *reinterpret_cast<const float4*>(&ksb[st * 64 + si * 16 + g * 4]);

        // ---- softmax with m=0: p = exp2(min(C2*qs + C2*ks - 2*C2*dot, 0))
        #pragma unroll
        for (int tf = 0; tf < 2; tf++) {
            float psum = 0.f;
            #pragma unroll
            for (int si = 0; si < 4; si++) {
                float kqa[4] = {kq[si].x, kq[si].y, kq[si].z, kq[si].w};
                float p[4];
                #pragma unroll
                for (int r = 0; r < 4; r++) {
                    float arg = fmaf(sacc[tf][si][r], M2C2, fmaf(kqa[r], C2, qsC[tf]));
                    p[r] = exp2f(fminf(arg, 0.f));
                    psum += p[r];
                }
                u32 w0 = cvtpk(p[0], p[1]), w1 = cvtpk(p[2], p[3]);
                int pg = ((si * 2 + (g >> 1)) ^ cmask);
                uint2v pw = {w0, w1};
                *reinterpret_cast<uint2v*>(&Ps[w][(tf * 16 + c) * 64 + pg * 8 + (g & 1) * 4]) = pw;
            }
            psum += __shfl_xor(psum, 16, 64);
            psum += __shfl_xor(psum, 32, 64);
            lrun[tf] += psum;
        }

        // ---- O += P.V
        short8 pa[2][2];
        #pragma unroll
        for (int tf = 0; tf < 2; tf++)
            #pragma unroll
            for (int sc = 0; sc < 2; sc++)
                pa[tf][sc] = *reinterpret_cast<const short8*>(
                    &Ps[w][(tf * 16 + c) * 64 + (((sc * 4 + g) ^ cmask) << 3)]);
        #pragma unroll
        for (int di = 0; di < 4; di++)
            #pragma unroll
            for (int sc = 0; sc < 2; sc++) {
                short8 vf = *reinterpret_cast<const short8*>(
                    &Vs[cur][(di * 16 + c) * 64 + (((sc * 4 + g) ^ cmask) << 3)]);
                #pragma unroll
                for (int tf = 0; tf < 2; tf++)
                    oacc[tf][di] = __builtin_amdgcn_mfma_f32_16x16x32_bf16(pa[tf][sc], vf, oacc[tf][di], 0, 0, 0);
            }

        __syncthreads();   // all waves done with cur; next tile drained
    }

    if (g == 0) { lLs[w][0][c] = lrun[0]; lLs[w][1][c] = lrun[1]; }
    #pragma unroll
    for (int tf = 0; tf < 2; tf++) {
        float linv[4];
        #pragma unroll
        for (int r = 0; r < 4; r++) linv[r] = __builtin_amdgcn_rcpf(lLs[w][tf][g * 4 + r]);
        #pragma unroll
        for (int di = 0; di < 4; di++)
            #pragma unroll
            for (int r = 0; r < 4; r++)
                ao[(size_t)(b * TSEQ + tw + tf * 16 + g * 4 + r) * CDIM + h * HDIM + di * 16 + c] =
                    f2bf(oacc[tf][di][r] * linv[r]);
    }
}

// ---------------------------------------------------------------------------
extern "C" void kernel_launch(void* const* d_in, const int* in_sizes, int n_in,
                              void* d_out, int out_size, void* d_ws, size_t ws_size,
                              hipStream_t stream) {
    const float* x  = (const float*)d_in[0];
    const float* Wq = (const float*)d_in[1];
    const float* gq = (const float*)d_in[2];
    const float* Wk = (const float*)d_in[3];
    const float* gk = (const float*)d_in[4];
    const float* Wv = (const float*)d_in[5];
    const float* gv = (const float*)d_in[6];
    const float* Wo = (const float*)d_in[7];
    float* out = (float*)d_out;

    char* p = (char*)d_ws;
    u16* xa  = (u16*)p;  p += (size_t)8 << 20;
    u16* qb  = (u16*)p;  p += (size_t)8 << 20;
    u16* kb  = (u16*)p;  p += (size_t)8 << 20;
    u16* vT  = (u16*)p;  p += (size_t)8 << 20;
    u16* ao  = (u16*)p;  p += (size_t)8 << 20;
    u16* waq = (u16*)p;  p += (size_t)2 << 20;
    u16* wak = (u16*)p;  p += (size_t)2 << 20;
    u16* wav = (u16*)p;  p += (size_t)2 << 20;
    u16* wob = (u16*)p;  p += (size_t)2 << 20;
    float* xsq  = (float*)p; p += 4096 * 4;
    float* sqq  = (float*)p; p += 1024 * 4;
    float* sqk  = (float*)p; p += 1024 * 4;
    float* sqv  = (float*)p; p += 1024 * 4;
    float* qsqT = (float*)p; p += 4096 * 16 * 4;
    float* ksqT = (float*)p; p += 4096 * 16 * 4;
    (void)ws_size; (void)in_sizes; (void)n_in; (void)out_size;

    prep<<<8192, 256, 0, stream>>>(x, Wq, Wk, Wv, Wo, xa, waq, wak, wav, wob,
                                   xsq, sqq, sqk, sqv);

    dim3 gqkv(8, 32, 3);
    gemm_qkv<<<gqkv, 256, 0, stream>>>(xa, waq, wak, wav, qb, kb, vT, xsq,
                                       sqq, sqk, sqv, gq, gk, gv, qsqT, ksqT);

    dim3 ga(16, NHEAD, 2);
    attn3<<<ga, 256, 0, stream>>>(qb, kb, vT, qsqT, ksqT, ao);

    dim3 gg(8, 32);
    gemm_out<<<gg, 256, 0, stream>>>(ao, wob, out);
}